// Round 2
// 886.181 us; speedup vs baseline: 1.1323x; 1.1323x over previous
//
#include <hip/hip_runtime.h>
#include <hip/hip_bf16.h>

#define NN 10000
#define NE 320000
#define F_NODE 128
#define F_EDGE 64
#define HID 128
#define LAT 64

using bf16 = __hip_bfloat16;
typedef float f32x4 __attribute__((ext_vector_type(4)));

// Runtime-dtype load: isbf selects bf16 vs f32 storage. Wave-uniform flag.
static __device__ __forceinline__ float ldf(const void* p, long i, int isbf) {
    if (isbf) return __bfloat162float(((const bf16*)p)[i]);
    return ((const float*)p)[i];
}

// ---------------- dtype detectors ----------------
// flags[0]=nf, flags[1]=ef, flags[2..13]=Wn1,bn1,We1,be1,Wm1,bm1,Wn2,bn2,We2,be2,Wm2,bm2
//   (1 = bf16 storage, 0 = f32 storage)
// flags[14]=src int64?, flags[15]=dst int64?  (1 = int64 words)
__global__ void k_detect(const void* nf, const void* ef,
                         const void* w0, const void* w1, const void* w2, const void* w3,
                         const void* w4, const void* w5, const void* w6, const void* w7,
                         const void* w8, const void* w9, const void* w10, const void* w11,
                         const int* srcp, const int* dstp, int* __restrict__ flags) {
    const void* ps[14] = {nf, ef, w0, w1, w2, w3, w4, w5, w6, w7, w8, w9, w10, w11};
    const int lens[14] = {NN * F_NODE, NE * F_EDGE,
                          16384, 128, 8192, 128, 16384, 128,
                          8192, 64, 4096, 64, 4096, 64};
    __shared__ int cntr;
    if (threadIdx.x == 0) cntr = 0;
    __syncthreads();
    int b = blockIdx.x;
    if (b < 14) {
        // f32 storage: even ushorts are low mantissa halves -> exponent field
        // ~uniform random (~72% outside [90,160]). bf16 storage: sane exponents.
        const unsigned short* raw = (const unsigned short*)ps[b];
        int S = lens[b] / 2; if (S > 2048) S = 2048;
        int c = 0;
        for (int i = threadIdx.x; i < S; i += 256) {
            unsigned short u = raw[2 * i];
            int e = (u >> 7) & 0xFF;
            if (e < 90 || e > 160) c++;
        }
        atomicAdd(&cntr, c);
        __syncthreads();
        if (threadIdx.x == 0) flags[b] = (10 * cntr > 3 * S) ? 0 : 1;
    } else {
        // int64 storage: odd words are high halves of small nonneg ints -> 0.
        const int* raw = (b == 14) ? srcp : dstp;
        int S = 2048;
        int c = 0;
        for (int i = threadIdx.x; i < S; i += 256) {
            if (raw[2 * i + 1] == 0) c++;
        }
        atomicAdd(&cntr, c);
        __syncthreads();
        if (threadIdx.x == 0) flags[b] = (2 * cntr > S) ? 1 : 0;
    }
}

// ---------------- weight/bias normalization to f32 ----------------
__global__ void k_convert_w(const void* w0, const void* w1, const void* w2, const void* w3,
                            const void* w4, const void* w5, const void* w6, const void* w7,
                            const void* w8, const void* w9, const void* w10, const void* w11,
                            const int* __restrict__ flags, float* __restrict__ wf) {
    const int WLEN[12] = {16384, 128, 8192, 128, 16384, 128, 8192, 64, 4096, 64, 4096, 64};
    const int WOFF[12] = {0, 16384, 16512, 24704, 24832, 41216, 41344, 49536, 49600, 53696, 53760, 57856};
    const void* ps[12] = {w0, w1, w2, w3, w4, w5, w6, w7, w8, w9, w10, w11};
    int t = blockIdx.x >> 6;
    int i = (blockIdx.x & 63) * 256 + threadIdx.x;
    if (i < WLEN[t]) wf[WOFF[t] + i] = ldf(ps[t], i, flags[2 + t]);
}

// ---------------- CSR build ----------------

__global__ void k_count(const int* __restrict__ dstp, const int* __restrict__ flags,
                        int* __restrict__ cnt) {
    int e = blockIdx.x * 256 + threadIdx.x;
    int w = flags[15];
    if (e < NE) atomicAdd(&cnt[dstp[(long)e << w]], 1);
}

__global__ void k_scan(const int* __restrict__ cnt, int* __restrict__ row_start) {
    __shared__ int buf[1024];
    __shared__ int carry;
    if (threadIdx.x == 0) carry = 0;
    __syncthreads();
    for (int base = 0; base < NN; base += 1024) {
        int i = base + threadIdx.x;
        int v = (i < NN) ? cnt[i] : 0;
        buf[threadIdx.x] = v;
        __syncthreads();
        for (int off = 1; off < 1024; off <<= 1) {
            int t = (threadIdx.x >= off) ? buf[threadIdx.x - off] : 0;
            __syncthreads();
            buf[threadIdx.x] += t;
            __syncthreads();
        }
        int excl = carry + buf[threadIdx.x] - v;
        if (i < NN) row_start[i] = excl;
        __syncthreads();
        if (threadIdx.x == 1023) carry += buf[1023];
        __syncthreads();
    }
    if (threadIdx.x == 0) row_start[NN] = carry;
}

__global__ void k_fill(const int* __restrict__ srcp, const int* __restrict__ dstp,
                       const int* __restrict__ flags,
                       const int* __restrict__ row_start, int* __restrict__ fill,
                       int2* __restrict__ epack) {
    int e = blockIdx.x * 256 + threadIdx.x;
    int ws_ = flags[14], wd = flags[15];
    if (e < NE) {
        int d = dstp[(long)e << wd];
        int s = srcp[(long)e << ws_];
        int pos = row_start[d] + atomicAdd(&fill[d], 1);
        epack[pos] = make_int2(e, s);
    }
}

// ---------------- Layer 1 ----------------
// h1[n] = relu( [(Sx/deg)@Wn1 + (Se/deg)@We1 + bn1 + be1] @ Wm1 + bm1 ),  0 if deg==0
__global__ void k_layer1(const void* __restrict__ nf, const void* __restrict__ ef,
                         const int* __restrict__ flags,
                         const int* __restrict__ row_start, const int* __restrict__ cnt,
                         const int2* __restrict__ epack,
                         const float* __restrict__ Wn1, const float* __restrict__ bn1,
                         const float* __restrict__ We1, const float* __restrict__ be1,
                         const float* __restrict__ Wm1, const float* __restrict__ bm1,
                         float* __restrict__ h1, float* __restrict__ bvec) {
    int n = blockIdx.x;
    int t = threadIdx.x;                       // 128 threads
    __shared__ float a_s[F_NODE], b_s[F_EDGE], t_s[HID];

    int fn = flags[0], fe = flags[1];
    int start = row_start[n], deg = cnt[n];
    float accx = 0.f, acce = 0.f;
    for (int i = 0; i < deg; i++) {
        int2 p = epack[start + i];
        accx += ldf(nf, (long)p.y * F_NODE + t, fn);
        if (t < F_EDGE) acce += ldf(ef, (long)p.x * F_EDGE + t, fe);
    }
    float inv = (deg > 0) ? (1.f / (float)deg) : 0.f;
    a_s[t] = accx * inv;
    if (t < F_EDGE) { b_s[t] = acce * inv; bvec[n * F_EDGE + t] = acce * inv; }
    __syncthreads();

    float acc = bn1[t] + be1[t];
    for (int k = 0; k < F_NODE; k++) acc += a_s[k] * Wn1[k * HID + t];
    for (int k = 0; k < F_EDGE; k++) acc += b_s[k] * We1[k * HID + t];
    t_s[t] = acc;
    __syncthreads();

    float o = bm1[t];
    for (int k = 0; k < HID; k++) o += t_s[k] * Wm1[k * HID + t];
    if (deg == 0) o = 0.f;
    o = fmaxf(o, 0.f);
    h1[n * HID + t] = o;
}

// ---------------- Layer 2 ----------------
__global__ void k_layer2(const float* __restrict__ h1, const float* __restrict__ bvec,
                         const int* __restrict__ row_start, const int* __restrict__ cnt,
                         const int2* __restrict__ epack,
                         const float* __restrict__ Wn2, const float* __restrict__ bn2,
                         const float* __restrict__ We2, const float* __restrict__ be2,
                         const float* __restrict__ Wm2, const float* __restrict__ bm2,
                         float* __restrict__ z, float* __restrict__ zout) {
    int n = blockIdx.x;
    int t = threadIdx.x;                       // 128 threads
    __shared__ float a_s[HID], b_s[F_EDGE], t_s[LAT];

    int start = row_start[n], deg = cnt[n];
    float accx = 0.f;
    for (int i = 0; i < deg; i++) {
        int2 p = epack[start + i];
        accx += h1[p.y * HID + t];
    }
    float inv = (deg > 0) ? (1.f / (float)deg) : 0.f;
    a_s[t] = accx * inv;
    if (t < F_EDGE) b_s[t] = bvec[n * F_EDGE + t];
    __syncthreads();

    if (t < LAT) {
        float acc = bn2[t] + be2[t];
        for (int k = 0; k < HID; k++) acc += a_s[k] * Wn2[k * LAT + t];
        for (int k = 0; k < F_EDGE; k++) acc += b_s[k] * We2[k * LAT + t];
        t_s[t] = acc;
    }
    __syncthreads();

    if (t < LAT) {
        float o = bm2[t];
        for (int k = 0; k < LAT; k++) o += t_s[k] * Wm2[k * LAT + t];
        if (deg == 0) o = 0.f;
        z[n * LAT + t] = o;
        zout[n * LAT + t] = o;            // f32 output
    }
}

// ---------------- adj = sigmoid(z @ z^T), f32 out ----------------
// 128x128 tile per 256-thread block, 8x8 per thread, K=64 fully resident in LDS.
// LDS layout: row-major [128][64] f32 with per-row XOR swizzle of the k index
// (phys_k = k ^ (row>>3 & 7), in float4 units) so that:
//   - staging ds_write_b128: 2-way bank aliasing (free)
//   - A-frag ds_read_b128 (fixed i, lanes vary ty): spread across bank groups
//   - B-frag ds_read_b128 (fixed j, lanes vary tx): 8 bank groups, 2-way (free)
__global__ __launch_bounds__(256, 2) void k_adj(const float* __restrict__ z,
                                                float* __restrict__ out) {
    __shared__ float As[128 * 64];
    __shared__ float Bs[128 * 64];
    const int t  = threadIdx.x;
    const int tx = t & 15;
    const int ty = t >> 4;
    const int r0 = blockIdx.y * 128;
    const int c0 = blockIdx.x * 128;

    // ---- stage A and B tiles (coalesced: wave reads 1KB contiguous of z) ----
    float4* As4w = (float4*)As;
    float4* Bs4w = (float4*)Bs;
#pragma unroll
    for (int it = 0; it < 8; ++it) {
        int idx = it * 256 + t;           // 0..2047
        int row = idx >> 4;               // 0..127
        int kq  = idx & 15;               // float4 index along k
        int sw  = (row >> 3) & 7;         // XOR swizzle (in float4 units)
        int gra = r0 + row;
        int grb = c0 + row;
        float4 va = make_float4(0.f, 0.f, 0.f, 0.f);
        float4 vb = make_float4(0.f, 0.f, 0.f, 0.f);
        if (gra < NN) va = *(const float4*)(z + (size_t)gra * LAT + kq * 4);
        if (grb < NN) vb = *(const float4*)(z + (size_t)grb * LAT + kq * 4);
        As4w[row * 16 + (kq ^ sw)] = va;
        Bs4w[row * 16 + (kq ^ sw)] = vb;
    }
    __syncthreads();

    // ---- 8x8 register tile, k in chunks of 4 via float4 LDS reads ----
    float acc[8][8] = {};
    const float4* As4 = (const float4*)As;
    const float4* Bs4 = (const float4*)Bs;
    const int sa = ty & 7;
    const int sb = tx & 7;

    for (int kb = 0; kb < 16; ++kb) {
        float4 a4[8], b4[8];
#pragma unroll
        for (int i = 0; i < 8; ++i)
            a4[i] = As4[(ty * 8 + i) * 16 + (kb ^ sa)];
#pragma unroll
        for (int j = 0; j < 8; ++j)
            b4[j] = Bs4[(tx * 8 + j) * 16 + (kb ^ sb)];
#pragma unroll
        for (int i = 0; i < 8; ++i)
#pragma unroll
            for (int j = 0; j < 8; ++j) {
                acc[i][j] += a4[i].x * b4[j].x;
                acc[i][j] += a4[i].y * b4[j].y;
                acc[i][j] += a4[i].z * b4[j].z;
                acc[i][j] += a4[i].w * b4[j].w;
            }
    }

    // ---- epilogue: sigmoid + nontemporal float4 stores (don't pollute L2) ----
#pragma unroll
    for (int i = 0; i < 8; ++i) {
        int gr = r0 + ty * 8 + i;
        if (gr >= NN) continue;
#pragma unroll
        for (int jj = 0; jj < 2; ++jj) {
            int gc = c0 + tx * 8 + jj * 4;
            if (gc + 3 < NN) {               // NN % 4 == 0: all-or-nothing per float4
                f32x4 pk;
                pk.x = 1.f / (1.f + __expf(-acc[i][jj * 4 + 0]));
                pk.y = 1.f / (1.f + __expf(-acc[i][jj * 4 + 1]));
                pk.z = 1.f / (1.f + __expf(-acc[i][jj * 4 + 2]));
                pk.w = 1.f / (1.f + __expf(-acc[i][jj * 4 + 3]));
                __builtin_nontemporal_store(pk, (f32x4*)(out + (size_t)gr * NN + gc));
            }
        }
    }
}

// ---------------- launch ----------------

extern "C" void kernel_launch(void* const* d_in, const int* in_sizes, int n_in,
                              void* d_out, int out_size, void* d_ws, size_t ws_size,
                              hipStream_t stream) {
    const void* nf  = d_in[0];
    const void* ef  = d_in[1];
    const int*  src = (const int*)d_in[2];
    const int*  dst = (const int*)d_in[3];
    const void* W[12];
    for (int i = 0; i < 12; i++) W[i] = d_in[4 + i];

    char* ws = (char*)d_ws;
    size_t off = 0;
    auto alloc = [&](size_t bytes) -> void* {
        void* p = ws + off;
        off = (off + bytes + 255) & ~(size_t)255;
        return p;
    };
    int*   flags     = (int*)alloc(16 * sizeof(int));
    float* wf        = (float*)alloc(57920 * sizeof(float));
    int*   cnt       = (int*)alloc(NN * sizeof(int));
    int*   fill      = (int*)alloc(NN * sizeof(int));
    int*   row_start = (int*)alloc((NN + 1) * sizeof(int));
    int2*  epack     = (int2*)alloc((size_t)NE * sizeof(int2));
    float* bvec      = (float*)alloc((size_t)NN * F_EDGE * sizeof(float));
    float* h1        = (float*)alloc((size_t)NN * HID * sizeof(float));
    float* zf        = (float*)alloc((size_t)NN * LAT * sizeof(float));

    hipMemsetAsync(cnt, 0, NN * sizeof(int), stream);
    hipMemsetAsync(fill, 0, NN * sizeof(int), stream);

    k_detect<<<16, 256, 0, stream>>>(nf, ef,
        W[0], W[1], W[2], W[3], W[4], W[5], W[6], W[7], W[8], W[9], W[10], W[11],
        src, dst, flags);
    k_convert_w<<<12 * 64, 256, 0, stream>>>(
        W[0], W[1], W[2], W[3], W[4], W[5], W[6], W[7], W[8], W[9], W[10], W[11],
        flags, wf);

    k_count<<<(NE + 255) / 256, 256, 0, stream>>>(dst, flags, cnt);
    k_scan<<<1, 1024, 0, stream>>>(cnt, row_start);
    k_fill<<<(NE + 255) / 256, 256, 0, stream>>>(src, dst, flags, row_start, fill, epack);

    const float* Wn1 = wf + 0,     *bn1 = wf + 16384;
    const float* We1 = wf + 16512, *be1 = wf + 24704;
    const float* Wm1 = wf + 24832, *bm1 = wf + 41216;
    const float* Wn2 = wf + 41344, *bn2 = wf + 49536;
    const float* We2 = wf + 49600, *be2 = wf + 53696;
    const float* Wm2 = wf + 53760, *bm2 = wf + 57856;

    k_layer1<<<NN, 128, 0, stream>>>(nf, ef, flags, row_start, cnt, epack,
                                     Wn1, bn1, We1, be1, Wm1, bm1, h1, bvec);
    k_layer2<<<NN, 128, 0, stream>>>(h1, bvec, row_start, cnt, epack,
                                     Wn2, bn2, We2, be2, Wm2, bm2,
                                     zf, (float*)d_out);

    dim3 g((NN + 127) / 128, (NN + 127) / 128);
    k_adj<<<g, 256, 0, stream>>>(zf, (float*)d_out + (size_t)NN * LAT);
}

// Round 3
// 884.937 us; speedup vs baseline: 1.1339x; 1.0014x over previous
//
#include <hip/hip_runtime.h>
#include <hip/hip_bf16.h>

#define NN 10000
#define NE 320000
#define F_NODE 128
#define F_EDGE 64
#define HID 128
#define LAT 64
#define NPB 4   // nodes per block in layer kernels

using bf16 = __hip_bfloat16;
typedef float f32x4 __attribute__((ext_vector_type(4)));

// Runtime-dtype load: isbf selects bf16 vs f32 storage. Wave-uniform flag.
static __device__ __forceinline__ float ldf(const void* p, long i, int isbf) {
    if (isbf) return __bfloat162float(((const bf16*)p)[i]);
    return ((const float*)p)[i];
}

// ---------------- dtype detectors ----------------
// flags[0]=nf, flags[1]=ef, flags[2..13]=Wn1,bn1,We1,be1,Wm1,bm1,Wn2,bn2,We2,be2,Wm2,bm2
//   (1 = bf16 storage, 0 = f32 storage)
// flags[14]=src int64?, flags[15]=dst int64?  (1 = int64 words)
__global__ void k_detect(const void* nf, const void* ef,
                         const void* w0, const void* w1, const void* w2, const void* w3,
                         const void* w4, const void* w5, const void* w6, const void* w7,
                         const void* w8, const void* w9, const void* w10, const void* w11,
                         const int* srcp, const int* dstp, int* __restrict__ flags) {
    const void* ps[14] = {nf, ef, w0, w1, w2, w3, w4, w5, w6, w7, w8, w9, w10, w11};
    const int lens[14] = {NN * F_NODE, NE * F_EDGE,
                          16384, 128, 8192, 128, 16384, 128,
                          8192, 64, 4096, 64, 4096, 64};
    __shared__ int cntr;
    if (threadIdx.x == 0) cntr = 0;
    __syncthreads();
    int b = blockIdx.x;
    if (b < 14) {
        // f32 storage: even ushorts are low mantissa halves -> exponent field
        // ~uniform random (~72% outside [90,160]). bf16 storage: sane exponents.
        const unsigned short* raw = (const unsigned short*)ps[b];
        int S = lens[b] / 2; if (S > 2048) S = 2048;
        int c = 0;
        for (int i = threadIdx.x; i < S; i += 256) {
            unsigned short u = raw[2 * i];
            int e = (u >> 7) & 0xFF;
            if (e < 90 || e > 160) c++;
        }
        atomicAdd(&cntr, c);
        __syncthreads();
        if (threadIdx.x == 0) flags[b] = (10 * cntr > 3 * S) ? 0 : 1;
    } else {
        // int64 storage: odd words are high halves of small nonneg ints -> 0.
        const int* raw = (b == 14) ? srcp : dstp;
        int S = 2048;
        int c = 0;
        for (int i = threadIdx.x; i < S; i += 256) {
            if (raw[2 * i + 1] == 0) c++;
        }
        atomicAdd(&cntr, c);
        __syncthreads();
        if (threadIdx.x == 0) flags[b] = (2 * cntr > S) ? 1 : 0;
    }
}

// ---------------- weight/bias normalization to f32 ----------------
__global__ void k_convert_w(const void* w0, const void* w1, const void* w2, const void* w3,
                            const void* w4, const void* w5, const void* w6, const void* w7,
                            const void* w8, const void* w9, const void* w10, const void* w11,
                            const int* __restrict__ flags, float* __restrict__ wf) {
    const int WLEN[12] = {16384, 128, 8192, 128, 16384, 128, 8192, 64, 4096, 64, 4096, 64};
    const int WOFF[12] = {0, 16384, 16512, 24704, 24832, 41216, 41344, 49536, 49600, 53696, 53760, 57856};
    const void* ps[12] = {w0, w1, w2, w3, w4, w5, w6, w7, w8, w9, w10, w11};
    int t = blockIdx.x >> 6;
    int i = (blockIdx.x & 63) * 256 + threadIdx.x;
    if (i < WLEN[t]) wf[WOFF[t] + i] = ldf(ps[t], i, flags[2 + t]);
}

// ---------------- CSR build ----------------

__global__ void k_count(const int* __restrict__ dstp, const int* __restrict__ flags,
                        int* __restrict__ cnt) {
    int e = blockIdx.x * 256 + threadIdx.x;
    int w = flags[15];
    if (e < NE) atomicAdd(&cnt[dstp[(long)e << w]], 1);
}

// 1024 threads; thread t serially scans 10 consecutive elements, wave-level
// __shfl_up scan of per-thread sums, then 16 wave sums scanned by thread 0.
// 2 barriers total (vs ~200 in the old Hillis-Steele version).
__global__ void k_scan(const int* __restrict__ cnt, int* __restrict__ row_start) {
    __shared__ int wsum[16];
    int t = threadIdx.x;
    int base = t * 10;
    int v[10];
    int s = 0;
#pragma unroll
    for (int i = 0; i < 10; i++) {
        v[i] = (base + i < NN) ? cnt[base + i] : 0;
        s += v[i];
    }
    int lane = t & 63;
    int x = s;
#pragma unroll
    for (int off = 1; off < 64; off <<= 1) {
        int y = __shfl_up(x, off, 64);
        if (lane >= off) x += y;
    }
    if (lane == 63) wsum[t >> 6] = x;
    __syncthreads();
    if (t == 0) {
        int c = 0;
#pragma unroll
        for (int i = 0; i < 16; i++) { int tmp = wsum[i]; wsum[i] = c; c += tmp; }
        row_start[NN] = c;
    }
    __syncthreads();
    int excl = wsum[t >> 6] + x - s;   // exclusive prefix at this thread's chunk start
#pragma unroll
    for (int i = 0; i < 10; i++) {
        if (base + i < NN) row_start[base + i] = excl;
        excl += v[i];
    }
}

__global__ void k_fill(const int* __restrict__ srcp, const int* __restrict__ dstp,
                       const int* __restrict__ flags,
                       const int* __restrict__ row_start, int* __restrict__ fill,
                       int2* __restrict__ epack) {
    int e = blockIdx.x * 256 + threadIdx.x;
    int ws_ = flags[14], wd = flags[15];
    if (e < NE) {
        int d = dstp[(long)e << wd];
        int s = srcp[(long)e << ws_];
        int pos = row_start[d] + atomicAdd(&fill[d], 1);
        epack[pos] = make_int2(e, s);
    }
}

// ---------------- Layer 1 ----------------
// 4 nodes per block: weight loads (the dominant VMEM cost) are shared 4x,
// and the 4 interleaved gather chains give 4x memory-level parallelism.
__global__ __launch_bounds__(128) void k_layer1(
        const void* __restrict__ nf, const void* __restrict__ ef,
        const int* __restrict__ flags,
        const int* __restrict__ row_start, const int* __restrict__ cnt,
        const int2* __restrict__ epack,
        const float* __restrict__ Wn1, const float* __restrict__ bn1,
        const float* __restrict__ We1, const float* __restrict__ be1,
        const float* __restrict__ Wm1, const float* __restrict__ bm1,
        float* __restrict__ h1, float* __restrict__ bvec) {
    int n0 = blockIdx.x * NPB;
    int t = threadIdx.x;                       // 128 threads
    __shared__ __align__(16) float a_s[NPB][F_NODE];
    __shared__ __align__(16) float b_s[NPB][F_EDGE];
    __shared__ __align__(16) float t_s[NPB][HID];

    int fn = flags[0], fe = flags[1];
    int start[NPB], deg[NPB];
    int md = 0;
#pragma unroll
    for (int l = 0; l < NPB; l++) {
        start[l] = row_start[n0 + l];
        deg[l]   = cnt[n0 + l];
        md = max(md, deg[l]);
    }
    float accx[NPB] = {}, acce[NPB] = {};
    for (int i = 0; i < md; i++) {
#pragma unroll
        for (int l = 0; l < NPB; l++) {
            if (i < deg[l]) {
                int2 p = epack[start[l] + i];
                accx[l] += ldf(nf, (long)p.y * F_NODE + t, fn);
                if (t < F_EDGE) acce[l] += ldf(ef, (long)p.x * F_EDGE + t, fe);
            }
        }
    }
#pragma unroll
    for (int l = 0; l < NPB; l++) {
        float inv = (deg[l] > 0) ? (1.f / (float)deg[l]) : 0.f;
        a_s[l][t] = accx[l] * inv;
        if (t < F_EDGE) {
            float b = acce[l] * inv;
            b_s[l][t] = b;
            bvec[(n0 + l) * F_EDGE + t] = b;
        }
    }
    __syncthreads();

    // stage 1: t_s = a@Wn1 + b@We1 + bn1 + be1
    float o[NPB];
    {
        float bb = bn1[t] + be1[t];
#pragma unroll
        for (int l = 0; l < NPB; l++) o[l] = bb;
    }
    for (int k = 0; k < F_NODE; k += 4) {
        float w0 = Wn1[(k + 0) * HID + t];
        float w1 = Wn1[(k + 1) * HID + t];
        float w2 = Wn1[(k + 2) * HID + t];
        float w3 = Wn1[(k + 3) * HID + t];
#pragma unroll
        for (int l = 0; l < NPB; l++) {
            float4 a = *(const float4*)&a_s[l][k];
            o[l] += a.x * w0 + a.y * w1 + a.z * w2 + a.w * w3;
        }
    }
    for (int k = 0; k < F_EDGE; k += 4) {
        float w0 = We1[(k + 0) * HID + t];
        float w1 = We1[(k + 1) * HID + t];
        float w2 = We1[(k + 2) * HID + t];
        float w3 = We1[(k + 3) * HID + t];
#pragma unroll
        for (int l = 0; l < NPB; l++) {
            float4 a = *(const float4*)&b_s[l][k];
            o[l] += a.x * w0 + a.y * w1 + a.z * w2 + a.w * w3;
        }
    }
#pragma unroll
    for (int l = 0; l < NPB; l++) t_s[l][t] = o[l];
    __syncthreads();

    // stage 2: h1 = relu(t_s @ Wm1 + bm1)
    float p[NPB];
    {
        float bb = bm1[t];
#pragma unroll
        for (int l = 0; l < NPB; l++) p[l] = bb;
    }
    for (int k = 0; k < HID; k += 4) {
        float w0 = Wm1[(k + 0) * HID + t];
        float w1 = Wm1[(k + 1) * HID + t];
        float w2 = Wm1[(k + 2) * HID + t];
        float w3 = Wm1[(k + 3) * HID + t];
#pragma unroll
        for (int l = 0; l < NPB; l++) {
            float4 a = *(const float4*)&t_s[l][k];
            p[l] += a.x * w0 + a.y * w1 + a.z * w2 + a.w * w3;
        }
    }
#pragma unroll
    for (int l = 0; l < NPB; l++) {
        float v = (deg[l] == 0) ? 0.f : p[l];
        h1[(n0 + l) * HID + t] = fmaxf(v, 0.f);
    }
}

// ---------------- Layer 2 ----------------
// 4 nodes per block. Gather uses all 128 lanes per node; matmul phase splits
// the two waves: wave g handles nodes {2g, 2g+1} on 64 output columns.
__global__ __launch_bounds__(128) void k_layer2(
        const float* __restrict__ h1, const float* __restrict__ bvec,
        const int* __restrict__ row_start, const int* __restrict__ cnt,
        const int2* __restrict__ epack,
        const float* __restrict__ Wn2, const float* __restrict__ bn2,
        const float* __restrict__ We2, const float* __restrict__ be2,
        const float* __restrict__ Wm2, const float* __restrict__ bm2,
        float* __restrict__ z, float* __restrict__ zout) {
    int n0 = blockIdx.x * NPB;
    int t = threadIdx.x;                       // 128 threads
    __shared__ __align__(16) float a_s[NPB][HID];
    __shared__ __align__(16) float b_s[NPB][F_EDGE];
    __shared__ __align__(16) float t_s[NPB][LAT];

    int start[NPB], deg[NPB];
    int md = 0;
#pragma unroll
    for (int l = 0; l < NPB; l++) {
        start[l] = row_start[n0 + l];
        deg[l]   = cnt[n0 + l];
        md = max(md, deg[l]);
    }
    float accx[NPB] = {};
    for (int i = 0; i < md; i++) {
#pragma unroll
        for (int l = 0; l < NPB; l++) {
            if (i < deg[l]) {
                int2 p = epack[start[l] + i];
                accx[l] += h1[p.y * HID + t];
            }
        }
    }
#pragma unroll
    for (int l = 0; l < NPB; l++) {
        float inv = (deg[l] > 0) ? (1.f / (float)deg[l]) : 0.f;
        a_s[l][t] = accx[l] * inv;
        if (t < F_EDGE) b_s[l][t] = bvec[(n0 + l) * F_EDGE + t];
    }
    __syncthreads();

    const int col = t & 63;
    const int g   = t >> 6;       // wave id: nodes 2g, 2g+1
    const int l0 = 2 * g, l1 = 2 * g + 1;

    float o0, o1;
    {
        float bb = bn2[col] + be2[col];
        o0 = bb; o1 = bb;
    }
    for (int k = 0; k < HID; k += 4) {
        float w0 = Wn2[(k + 0) * LAT + col];
        float w1 = Wn2[(k + 1) * LAT + col];
        float w2 = Wn2[(k + 2) * LAT + col];
        float w3 = Wn2[(k + 3) * LAT + col];
        float4 a0 = *(const float4*)&a_s[l0][k];
        float4 a1 = *(const float4*)&a_s[l1][k];
        o0 += a0.x * w0 + a0.y * w1 + a0.z * w2 + a0.w * w3;
        o1 += a1.x * w0 + a1.y * w1 + a1.z * w2 + a1.w * w3;
    }
    for (int k = 0; k < F_EDGE; k += 4) {
        float w0 = We2[(k + 0) * LAT + col];
        float w1 = We2[(k + 1) * LAT + col];
        float w2 = We2[(k + 2) * LAT + col];
        float w3 = We2[(k + 3) * LAT + col];
        float4 a0 = *(const float4*)&b_s[l0][k];
        float4 a1 = *(const float4*)&b_s[l1][k];
        o0 += a0.x * w0 + a0.y * w1 + a0.z * w2 + a0.w * w3;
        o1 += a1.x * w0 + a1.y * w1 + a1.z * w2 + a1.w * w3;
    }
    t_s[l0][col] = o0;
    t_s[l1][col] = o1;
    __syncthreads();

    float p0, p1;
    {
        float bb = bm2[col];
        p0 = bb; p1 = bb;
    }
    for (int k = 0; k < LAT; k += 4) {
        float w0 = Wm2[(k + 0) * LAT + col];
        float w1 = Wm2[(k + 1) * LAT + col];
        float w2 = Wm2[(k + 2) * LAT + col];
        float w3 = Wm2[(k + 3) * LAT + col];
        float4 a0 = *(const float4*)&t_s[l0][k];
        float4 a1 = *(const float4*)&t_s[l1][k];
        p0 += a0.x * w0 + a0.y * w1 + a0.z * w2 + a0.w * w3;
        p1 += a1.x * w0 + a1.y * w1 + a1.z * w2 + a1.w * w3;
    }
    if (deg[l0] == 0) p0 = 0.f;
    if (deg[l1] == 0) p1 = 0.f;
    z[(n0 + l0) * LAT + col] = p0;
    z[(n0 + l1) * LAT + col] = p1;
    zout[(n0 + l0) * LAT + col] = p0;
    zout[(n0 + l1) * LAT + col] = p1;
}

// ---------------- adj = sigmoid(z @ z^T), f32 out ----------------
// Symmetric: only tiles with bi <= bj compute; each off-diagonal tile is
// stored twice (direct + mirrored). Mirrored elements are bitwise identical
// (same k-order summation). 128x128 tile, 8x8 per thread, K=64 in LDS with
// XOR-swizzled float4 rows.
__global__ __launch_bounds__(256, 2) void k_adj(const float* __restrict__ z,
                                                float* __restrict__ out) {
    const int bi = blockIdx.y;   // row tile
    const int bj = blockIdx.x;   // col tile
    if (bi > bj) return;

    __shared__ float As[128 * 64];
    __shared__ float Bs[128 * 64];
    const int t  = threadIdx.x;
    const int tx = t & 15;
    const int ty = t >> 4;
    const int r0 = bi * 128;
    const int c0 = bj * 128;

    // ---- stage A and B tiles (coalesced: wave reads 1KB contiguous of z) ----
    float4* As4w = (float4*)As;
    float4* Bs4w = (float4*)Bs;
#pragma unroll
    for (int it = 0; it < 8; ++it) {
        int idx = it * 256 + t;           // 0..2047
        int row = idx >> 4;               // 0..127
        int kq  = idx & 15;               // float4 index along k
        int sw  = (row >> 3) & 7;         // XOR swizzle (in float4 units)
        int gra = r0 + row;
        int grb = c0 + row;
        float4 va = make_float4(0.f, 0.f, 0.f, 0.f);
        float4 vb = make_float4(0.f, 0.f, 0.f, 0.f);
        if (gra < NN) va = *(const float4*)(z + (size_t)gra * LAT + kq * 4);
        if (grb < NN) vb = *(const float4*)(z + (size_t)grb * LAT + kq * 4);
        As4w[row * 16 + (kq ^ sw)] = va;
        Bs4w[row * 16 + (kq ^ sw)] = vb;
    }
    __syncthreads();

    // ---- 8x8 register tile, k in chunks of 4 via float4 LDS reads ----
    float acc[8][8] = {};
    const float4* As4 = (const float4*)As;
    const float4* Bs4 = (const float4*)Bs;
    const int sa = ty & 7;
    const int sb = tx & 7;

    for (int kb = 0; kb < 16; ++kb) {
        float4 a4[8], b4[8];
#pragma unroll
        for (int i = 0; i < 8; ++i)
            a4[i] = As4[(ty * 8 + i) * 16 + (kb ^ sa)];
#pragma unroll
        for (int j = 0; j < 8; ++j)
            b4[j] = Bs4[(tx * 8 + j) * 16 + (kb ^ sb)];
#pragma unroll
        for (int i = 0; i < 8; ++i)
#pragma unroll
            for (int j = 0; j < 8; ++j) {
                acc[i][j] += a4[i].x * b4[j].x;
                acc[i][j] += a4[i].y * b4[j].y;
                acc[i][j] += a4[i].z * b4[j].z;
                acc[i][j] += a4[i].w * b4[j].w;
            }
    }

    // ---- sigmoid in place ----
#pragma unroll
    for (int i = 0; i < 8; ++i)
#pragma unroll
        for (int j = 0; j < 8; ++j)
            acc[i][j] = 1.f / (1.f + __expf(-acc[i][j]));

    // ---- direct tile store (nontemporal float4) ----
#pragma unroll
    for (int i = 0; i < 8; ++i) {
        int gr = r0 + ty * 8 + i;
        if (gr >= NN) continue;
#pragma unroll
        for (int jj = 0; jj < 2; ++jj) {
            int gc = c0 + tx * 8 + jj * 4;
            if (gc + 3 < NN) {               // NN % 4 == 0: all-or-nothing per float4
                f32x4 pk = {acc[i][jj * 4 + 0], acc[i][jj * 4 + 1],
                            acc[i][jj * 4 + 2], acc[i][jj * 4 + 3]};
                __builtin_nontemporal_store(pk, (f32x4*)(out + (size_t)gr * NN + gc));
            }
        }
    }

    // ---- mirrored tile store (bi < bj strictly => rows r0..r0+127 all valid) ----
    if (bi != bj) {
#pragma unroll
        for (int j = 0; j < 8; ++j) {
            int gc = c0 + tx * 8 + j;        // row index of mirrored tile
            if (gc >= NN) continue;
#pragma unroll
            for (int ii = 0; ii < 2; ++ii) {
                int gr = r0 + ty * 8 + ii * 4;   // col base of mirrored tile
                if (gr + 3 < NN) {
                    f32x4 pk = {acc[ii * 4 + 0][j], acc[ii * 4 + 1][j],
                                acc[ii * 4 + 2][j], acc[ii * 4 + 3][j]};
                    __builtin_nontemporal_store(pk, (f32x4*)(out + (size_t)gc * NN + gr));
                }
            }
        }
    }
}

// ---------------- launch ----------------

extern "C" void kernel_launch(void* const* d_in, const int* in_sizes, int n_in,
                              void* d_out, int out_size, void* d_ws, size_t ws_size,
                              hipStream_t stream) {
    const void* nf  = d_in[0];
    const void* ef  = d_in[1];
    const int*  src = (const int*)d_in[2];
    const int*  dst = (const int*)d_in[3];
    const void* W[12];
    for (int i = 0; i < 12; i++) W[i] = d_in[4 + i];

    char* ws = (char*)d_ws;
    size_t off = 0;
    auto alloc = [&](size_t bytes) -> void* {
        void* p = ws + off;
        off = (off + bytes + 255) & ~(size_t)255;
        return p;
    };
    int*   flags     = (int*)alloc(16 * sizeof(int));
    float* wf        = (float*)alloc(57920 * sizeof(float));
    int*   cnt       = (int*)alloc(NN * sizeof(int));
    int*   fill      = (int*)alloc(NN * sizeof(int));
    int*   row_start = (int*)alloc((NN + 1) * sizeof(int));
    int2*  epack     = (int2*)alloc((size_t)NE * sizeof(int2));
    float* bvec      = (float*)alloc((size_t)NN * F_EDGE * sizeof(float));
    float* h1        = (float*)alloc((size_t)NN * HID * sizeof(float));
    float* zf        = (float*)alloc((size_t)NN * LAT * sizeof(float));

    hipMemsetAsync(cnt, 0, NN * sizeof(int), stream);
    hipMemsetAsync(fill, 0, NN * sizeof(int), stream);

    k_detect<<<16, 256, 0, stream>>>(nf, ef,
        W[0], W[1], W[2], W[3], W[4], W[5], W[6], W[7], W[8], W[9], W[10], W[11],
        src, dst, flags);
    k_convert_w<<<12 * 64, 256, 0, stream>>>(
        W[0], W[1], W[2], W[3], W[4], W[5], W[6], W[7], W[8], W[9], W[10], W[11],
        flags, wf);

    k_count<<<(NE + 255) / 256, 256, 0, stream>>>(dst, flags, cnt);
    k_scan<<<1, 1024, 0, stream>>>(cnt, row_start);
    k_fill<<<(NE + 255) / 256, 256, 0, stream>>>(src, dst, flags, row_start, fill, epack);

    const float* Wn1 = wf + 0,     *bn1 = wf + 16384;
    const float* We1 = wf + 16512, *be1 = wf + 24704;
    const float* Wm1 = wf + 24832, *bm1 = wf + 41216;
    const float* Wn2 = wf + 41344, *bn2 = wf + 49536;
    const float* We2 = wf + 49600, *be2 = wf + 53696;
    const float* Wm2 = wf + 53760, *bm2 = wf + 57856;

    k_layer1<<<NN / NPB, 128, 0, stream>>>(nf, ef, flags, row_start, cnt, epack,
                                           Wn1, bn1, We1, be1, Wm1, bm1, h1, bvec);
    k_layer2<<<NN / NPB, 128, 0, stream>>>(h1, bvec, row_start, cnt, epack,
                                           Wn2, bn2, We2, be2, Wm2, bm2,
                                           zf, (float*)d_out);

    dim3 g((NN + 127) / 128, (NN + 127) / 128);
    k_adj<<<g, 256, 0, stream>>>(zf, (float*)d_out + (size_t)NN * LAT);
}

// Round 4
// 771.036 us; speedup vs baseline: 1.3014x; 1.1477x over previous
//
#include <hip/hip_runtime.h>
#include <hip/hip_bf16.h>

#define NN 10000
#define NE 320000
#define F_NODE 128
#define F_EDGE 64
#define HID 128
#define LAT 64
#define NPB 4   // nodes per block in layer kernels

using bf16 = __hip_bfloat16;
typedef float f32x4 __attribute__((ext_vector_type(4)));

// Runtime-dtype load: isbf selects bf16 vs f32 storage. Wave-uniform flag.
static __device__ __forceinline__ float ldf(const void* p, long i, int isbf) {
    if (isbf) return __bfloat162float(((const bf16*)p)[i]);
    return ((const float*)p)[i];
}

// ---------------- dtype detectors ----------------
// flags[0]=nf, flags[1]=ef, flags[2..13]=Wn1,bn1,We1,be1,Wm1,bm1,Wn2,bn2,We2,be2,Wm2,bm2
//   (1 = bf16 storage, 0 = f32 storage)
// flags[14]=src int64?, flags[15]=dst int64?  (1 = int64 words)
__global__ void k_detect(const void* nf, const void* ef,
                         const void* w0, const void* w1, const void* w2, const void* w3,
                         const void* w4, const void* w5, const void* w6, const void* w7,
                         const void* w8, const void* w9, const void* w10, const void* w11,
                         const int* srcp, const int* dstp, int* __restrict__ flags) {
    const void* ps[14] = {nf, ef, w0, w1, w2, w3, w4, w5, w6, w7, w8, w9, w10, w11};
    const int lens[14] = {NN * F_NODE, NE * F_EDGE,
                          16384, 128, 8192, 128, 16384, 128,
                          8192, 64, 4096, 64, 4096, 64};
    __shared__ int cntr;
    if (threadIdx.x == 0) cntr = 0;
    __syncthreads();
    int b = blockIdx.x;
    if (b < 14) {
        // f32 storage: even ushorts are low mantissa halves -> exponent field
        // ~uniform random (~72% outside [90,160]). bf16 storage: sane exponents.
        const unsigned short* raw = (const unsigned short*)ps[b];
        int S = lens[b] / 2; if (S > 2048) S = 2048;
        int c = 0;
        for (int i = threadIdx.x; i < S; i += 256) {
            unsigned short u = raw[2 * i];
            int e = (u >> 7) & 0xFF;
            if (e < 90 || e > 160) c++;
        }
        atomicAdd(&cntr, c);
        __syncthreads();
        if (threadIdx.x == 0) flags[b] = (10 * cntr > 3 * S) ? 0 : 1;
    } else {
        // int64 storage: odd words are high halves of small nonneg ints -> 0.
        const int* raw = (b == 14) ? srcp : dstp;
        int S = 2048;
        int c = 0;
        for (int i = threadIdx.x; i < S; i += 256) {
            if (raw[2 * i + 1] == 0) c++;
        }
        atomicAdd(&cntr, c);
        __syncthreads();
        if (threadIdx.x == 0) flags[b] = (2 * cntr > S) ? 1 : 0;
    }
}

// ---------------- weight/bias normalization to f32 ----------------
__global__ void k_convert_w(const void* w0, const void* w1, const void* w2, const void* w3,
                            const void* w4, const void* w5, const void* w6, const void* w7,
                            const void* w8, const void* w9, const void* w10, const void* w11,
                            const int* __restrict__ flags, float* __restrict__ wf) {
    const int WLEN[12] = {16384, 128, 8192, 128, 16384, 128, 8192, 64, 4096, 64, 4096, 64};
    const int WOFF[12] = {0, 16384, 16512, 24704, 24832, 41216, 41344, 49536, 49600, 53696, 53760, 57856};
    const void* ps[12] = {w0, w1, w2, w3, w4, w5, w6, w7, w8, w9, w10, w11};
    int t = blockIdx.x >> 6;
    int i = (blockIdx.x & 63) * 256 + threadIdx.x;
    if (i < WLEN[t]) wf[WOFF[t] + i] = ldf(ps[t], i, flags[2 + t]);
}

// ---------------- CSR build ----------------

__global__ void k_count(const int* __restrict__ dstp, const int* __restrict__ flags,
                        int* __restrict__ cnt) {
    int e = blockIdx.x * 256 + threadIdx.x;
    int w = flags[15];
    if (e < NE) atomicAdd(&cnt[dstp[(long)e << w]], 1);
}

// 1024 threads; thread t serially scans 10 consecutive elements, wave-level
// __shfl_up scan of per-thread sums, then 16 wave sums scanned by thread 0.
__global__ void k_scan(const int* __restrict__ cnt, int* __restrict__ row_start) {
    __shared__ int wsum[16];
    int t = threadIdx.x;
    int base = t * 10;
    int v[10];
    int s = 0;
#pragma unroll
    for (int i = 0; i < 10; i++) {
        v[i] = (base + i < NN) ? cnt[base + i] : 0;
        s += v[i];
    }
    int lane = t & 63;
    int x = s;
#pragma unroll
    for (int off = 1; off < 64; off <<= 1) {
        int y = __shfl_up(x, off, 64);
        if (lane >= off) x += y;
    }
    if (lane == 63) wsum[t >> 6] = x;
    __syncthreads();
    if (t == 0) {
        int c = 0;
#pragma unroll
        for (int i = 0; i < 16; i++) { int tmp = wsum[i]; wsum[i] = c; c += tmp; }
        row_start[NN] = c;
    }
    __syncthreads();
    int excl = wsum[t >> 6] + x - s;   // exclusive prefix at this thread's chunk start
#pragma unroll
    for (int i = 0; i < 10; i++) {
        if (base + i < NN) row_start[base + i] = excl;
        excl += v[i];
    }
}

__global__ void k_fill(const int* __restrict__ srcp, const int* __restrict__ dstp,
                       const int* __restrict__ flags,
                       const int* __restrict__ row_start, int* __restrict__ fill,
                       int2* __restrict__ epack) {
    int e = blockIdx.x * 256 + threadIdx.x;
    int ws_ = flags[14], wd = flags[15];
    if (e < NE) {
        int d = dstp[(long)e << wd];
        int s = srcp[(long)e << ws_];
        int pos = row_start[d] + atomicAdd(&fill[d], 1);
        epack[pos] = make_int2(e, s);
    }
}

// ---------------- Layer 1 ----------------
// 4 nodes per block: weight loads (the dominant VMEM cost) are shared 4x,
// and the 4 interleaved gather chains give 4x memory-level parallelism.
__global__ __launch_bounds__(128) void k_layer1(
        const void* __restrict__ nf, const void* __restrict__ ef,
        const int* __restrict__ flags,
        const int* __restrict__ row_start, const int* __restrict__ cnt,
        const int2* __restrict__ epack,
        const float* __restrict__ Wn1, const float* __restrict__ bn1,
        const float* __restrict__ We1, const float* __restrict__ be1,
        const float* __restrict__ Wm1, const float* __restrict__ bm1,
        float* __restrict__ h1, float* __restrict__ bvec) {
    int n0 = blockIdx.x * NPB;
    int t = threadIdx.x;                       // 128 threads
    __shared__ __align__(16) float a_s[NPB][F_NODE];
    __shared__ __align__(16) float b_s[NPB][F_EDGE];
    __shared__ __align__(16) float t_s[NPB][HID];

    int fn = flags[0], fe = flags[1];
    int start[NPB], deg[NPB];
    int md = 0;
#pragma unroll
    for (int l = 0; l < NPB; l++) {
        start[l] = row_start[n0 + l];
        deg[l]   = cnt[n0 + l];
        md = max(md, deg[l]);
    }
    float accx[NPB] = {}, acce[NPB] = {};
    for (int i = 0; i < md; i++) {
#pragma unroll
        for (int l = 0; l < NPB; l++) {
            if (i < deg[l]) {
                int2 p = epack[start[l] + i];
                accx[l] += ldf(nf, (long)p.y * F_NODE + t, fn);
                if (t < F_EDGE) acce[l] += ldf(ef, (long)p.x * F_EDGE + t, fe);
            }
        }
    }
#pragma unroll
    for (int l = 0; l < NPB; l++) {
        float inv = (deg[l] > 0) ? (1.f / (float)deg[l]) : 0.f;
        a_s[l][t] = accx[l] * inv;
        if (t < F_EDGE) {
            float b = acce[l] * inv;
            b_s[l][t] = b;
            bvec[(n0 + l) * F_EDGE + t] = b;
        }
    }
    __syncthreads();

    // stage 1: t_s = a@Wn1 + b@We1 + bn1 + be1
    float o[NPB];
    {
        float bb = bn1[t] + be1[t];
#pragma unroll
        for (int l = 0; l < NPB; l++) o[l] = bb;
    }
    for (int k = 0; k < F_NODE; k += 4) {
        float w0 = Wn1[(k + 0) * HID + t];
        float w1 = Wn1[(k + 1) * HID + t];
        float w2 = Wn1[(k + 2) * HID + t];
        float w3 = Wn1[(k + 3) * HID + t];
#pragma unroll
        for (int l = 0; l < NPB; l++) {
            float4 a = *(const float4*)&a_s[l][k];
            o[l] += a.x * w0 + a.y * w1 + a.z * w2 + a.w * w3;
        }
    }
    for (int k = 0; k < F_EDGE; k += 4) {
        float w0 = We1[(k + 0) * HID + t];
        float w1 = We1[(k + 1) * HID + t];
        float w2 = We1[(k + 2) * HID + t];
        float w3 = We1[(k + 3) * HID + t];
#pragma unroll
        for (int l = 0; l < NPB; l++) {
            float4 a = *(const float4*)&b_s[l][k];
            o[l] += a.x * w0 + a.y * w1 + a.z * w2 + a.w * w3;
        }
    }
#pragma unroll
    for (int l = 0; l < NPB; l++) t_s[l][t] = o[l];
    __syncthreads();

    // stage 2: h1 = relu(t_s @ Wm1 + bm1)
    float p[NPB];
    {
        float bb = bm1[t];
#pragma unroll
        for (int l = 0; l < NPB; l++) p[l] = bb;
    }
    for (int k = 0; k < HID; k += 4) {
        float w0 = Wm1[(k + 0) * HID + t];
        float w1 = Wm1[(k + 1) * HID + t];
        float w2 = Wm1[(k + 2) * HID + t];
        float w3 = Wm1[(k + 3) * HID + t];
#pragma unroll
        for (int l = 0; l < NPB; l++) {
            float4 a = *(const float4*)&t_s[l][k];
            p[l] += a.x * w0 + a.y * w1 + a.z * w2 + a.w * w3;
        }
    }
#pragma unroll
    for (int l = 0; l < NPB; l++) {
        float v = (deg[l] == 0) ? 0.f : p[l];
        h1[(n0 + l) * HID + t] = fmaxf(v, 0.f);
    }
}

// ---------------- Layer 2 ----------------
// 4 nodes per block. Gather uses all 128 lanes per node; matmul phase splits
// the two waves: wave g handles nodes {2g, 2g+1} on 64 output columns.
__global__ __launch_bounds__(128) void k_layer2(
        const float* __restrict__ h1, const float* __restrict__ bvec,
        const int* __restrict__ row_start, const int* __restrict__ cnt,
        const int2* __restrict__ epack,
        const float* __restrict__ Wn2, const float* __restrict__ bn2,
        const float* __restrict__ We2, const float* __restrict__ be2,
        const float* __restrict__ Wm2, const float* __restrict__ bm2,
        float* __restrict__ z, float* __restrict__ zout) {
    int n0 = blockIdx.x * NPB;
    int t = threadIdx.x;                       // 128 threads
    __shared__ __align__(16) float a_s[NPB][HID];
    __shared__ __align__(16) float b_s[NPB][F_EDGE];
    __shared__ __align__(16) float t_s[NPB][LAT];

    int start[NPB], deg[NPB];
    int md = 0;
#pragma unroll
    for (int l = 0; l < NPB; l++) {
        start[l] = row_start[n0 + l];
        deg[l]   = cnt[n0 + l];
        md = max(md, deg[l]);
    }
    float accx[NPB] = {};
    for (int i = 0; i < md; i++) {
#pragma unroll
        for (int l = 0; l < NPB; l++) {
            if (i < deg[l]) {
                int2 p = epack[start[l] + i];
                accx[l] += h1[p.y * HID + t];
            }
        }
    }
#pragma unroll
    for (int l = 0; l < NPB; l++) {
        float inv = (deg[l] > 0) ? (1.f / (float)deg[l]) : 0.f;
        a_s[l][t] = accx[l] * inv;
        if (t < F_EDGE) b_s[l][t] = bvec[(n0 + l) * F_EDGE + t];
    }
    __syncthreads();

    const int col = t & 63;
    const int g   = t >> 6;       // wave id: nodes 2g, 2g+1
    const int l0 = 2 * g, l1 = 2 * g + 1;

    float o0, o1;
    {
        float bb = bn2[col] + be2[col];
        o0 = bb; o1 = bb;
    }
    for (int k = 0; k < HID; k += 4) {
        float w0 = Wn2[(k + 0) * LAT + col];
        float w1 = Wn2[(k + 1) * LAT + col];
        float w2 = Wn2[(k + 2) * LAT + col];
        float w3 = Wn2[(k + 3) * LAT + col];
        float4 a0 = *(const float4*)&a_s[l0][k];
        float4 a1 = *(const float4*)&a_s[l1][k];
        o0 += a0.x * w0 + a0.y * w1 + a0.z * w2 + a0.w * w3;
        o1 += a1.x * w0 + a1.y * w1 + a1.z * w2 + a1.w * w3;
    }
    for (int k = 0; k < F_EDGE; k += 4) {
        float w0 = We2[(k + 0) * LAT + col];
        float w1 = We2[(k + 1) * LAT + col];
        float w2 = We2[(k + 2) * LAT + col];
        float w3 = We2[(k + 3) * LAT + col];
        float4 a0 = *(const float4*)&b_s[l0][k];
        float4 a1 = *(const float4*)&b_s[l1][k];
        o0 += a0.x * w0 + a0.y * w1 + a0.z * w2 + a0.w * w3;
        o1 += a1.x * w0 + a1.y * w1 + a1.z * w2 + a1.w * w3;
    }
    t_s[l0][col] = o0;
    t_s[l1][col] = o1;
    __syncthreads();

    float p0, p1;
    {
        float bb = bm2[col];
        p0 = bb; p1 = bb;
    }
    for (int k = 0; k < LAT; k += 4) {
        float w0 = Wm2[(k + 0) * LAT + col];
        float w1 = Wm2[(k + 1) * LAT + col];
        float w2 = Wm2[(k + 2) * LAT + col];
        float w3 = Wm2[(k + 3) * LAT + col];
        float4 a0 = *(const float4*)&t_s[l0][k];
        float4 a1 = *(const float4*)&t_s[l1][k];
        p0 += a0.x * w0 + a0.y * w1 + a0.z * w2 + a0.w * w3;
        p1 += a1.x * w0 + a1.y * w1 + a1.z * w2 + a1.w * w3;
    }
    if (deg[l0] == 0) p0 = 0.f;
    if (deg[l1] == 0) p1 = 0.f;
    z[(n0 + l0) * LAT + col] = p0;
    z[(n0 + l1) * LAT + col] = p1;
    zout[(n0 + l0) * LAT + col] = p0;
    zout[(n0 + l1) * LAT + col] = p1;
}

// ---------------- adj = sigmoid(z @ z^T), f32 out ----------------
// Symmetric: only tiles with bi <= bj compute. Off-diagonal tiles are stored
// twice: direct (coalesced from registers) and mirrored via an LDS transpose
// (reusing the 64KB staging buffers) so the mirror store is ALSO fully
// coalesced full-row traffic. Mirror values bitwise identical to direct.
__global__ __launch_bounds__(256, 2) void k_adj(const float* __restrict__ z,
                                                float* __restrict__ out) {
    const int bi = blockIdx.y;   // row tile
    const int bj = blockIdx.x;   // col tile
    if (bi > bj) return;

    __shared__ __align__(16) float smem[128 * 128];   // As | Bs, later transpose buf
    float* As = smem;                 // 128 x 64
    float* Bs = smem + 128 * 64;      // 128 x 64
    const int t  = threadIdx.x;
    const int tx = t & 15;
    const int ty = t >> 4;
    const int r0 = bi * 128;
    const int c0 = bj * 128;

    // ---- stage A and B tiles (coalesced: wave reads 1KB contiguous of z) ----
    float4* As4w = (float4*)As;
    float4* Bs4w = (float4*)Bs;
#pragma unroll
    for (int it = 0; it < 8; ++it) {
        int idx = it * 256 + t;           // 0..2047
        int row = idx >> 4;               // 0..127
        int kq  = idx & 15;               // float4 index along k
        int sw  = (row >> 3) & 7;         // XOR swizzle (in float4 units)
        int gra = r0 + row;
        int grb = c0 + row;
        float4 va = make_float4(0.f, 0.f, 0.f, 0.f);
        float4 vb = make_float4(0.f, 0.f, 0.f, 0.f);
        if (gra < NN) va = *(const float4*)(z + (size_t)gra * LAT + kq * 4);
        if (grb < NN) vb = *(const float4*)(z + (size_t)grb * LAT + kq * 4);
        As4w[row * 16 + (kq ^ sw)] = va;
        Bs4w[row * 16 + (kq ^ sw)] = vb;
    }
    __syncthreads();

    // ---- 8x8 register tile, k in chunks of 4 via float4 LDS reads ----
    float acc[8][8] = {};
    {
        const float4* As4 = (const float4*)As;
        const float4* Bs4 = (const float4*)Bs;
        const int sa = ty & 7;
        const int sb = tx & 7;
        for (int kb = 0; kb < 16; ++kb) {
            float4 a4[8], b4[8];
#pragma unroll
            for (int i = 0; i < 8; ++i)
                a4[i] = As4[(ty * 8 + i) * 16 + (kb ^ sa)];
#pragma unroll
            for (int j = 0; j < 8; ++j)
                b4[j] = Bs4[(tx * 8 + j) * 16 + (kb ^ sb)];
#pragma unroll
            for (int i = 0; i < 8; ++i)
#pragma unroll
                for (int j = 0; j < 8; ++j) {
                    acc[i][j] += a4[i].x * b4[j].x;
                    acc[i][j] += a4[i].y * b4[j].y;
                    acc[i][j] += a4[i].z * b4[j].z;
                    acc[i][j] += a4[i].w * b4[j].w;
                }
        }
    }

    // ---- sigmoid in place ----
#pragma unroll
    for (int i = 0; i < 8; ++i)
#pragma unroll
        for (int j = 0; j < 8; ++j)
            acc[i][j] = 1.f / (1.f + __expf(-acc[i][j]));

    // ---- direct tile store (nontemporal float4) ----
#pragma unroll
    for (int i = 0; i < 8; ++i) {
        int gr = r0 + ty * 8 + i;
        if (gr < NN) {
#pragma unroll
            for (int jj = 0; jj < 2; ++jj) {
                int gc = c0 + tx * 8 + jj * 4;
                if (gc + 3 < NN) {           // NN % 4 == 0: all-or-nothing per float4
                    f32x4 pk = {acc[i][jj * 4 + 0], acc[i][jj * 4 + 1],
                                acc[i][jj * 4 + 2], acc[i][jj * 4 + 3]};
                    __builtin_nontemporal_store(pk, (f32x4*)(out + (size_t)gr * NN + gc));
                }
            }
        }
    }

    // ---- mirrored tile via LDS transpose (fully coalesced row stores) ----
    if (bi != bj) {
        __syncthreads();                    // staging buffers now dead; reuse as T
        float4* T4 = (float4*)smem;         // 128 rows (b = tile col) x 32 chunks
        const int swT = tx & 7;             // = (b>>3)&7 since b = tx*8+j
#pragma unroll
        for (int j = 0; j < 8; ++j) {
            int b = tx * 8 + j;             // tile column = mirror row
#pragma unroll
            for (int ii = 0; ii < 2; ++ii) {
                int ca = ty * 2 + ii;       // chunk along tile-row axis (a = ca*4..+3)
                float4 v;
                v.x = acc[ii * 4 + 0][j];
                v.y = acc[ii * 4 + 1][j];
                v.z = acc[ii * 4 + 2][j];
                v.w = acc[ii * 4 + 3][j];
                T4[b * 32 + (ca ^ swT)] = v;
            }
        }
        __syncthreads();
        // read back: 64 lanes cover 2 full rows of 512B each -> coalesced stores
#pragma unroll
        for (int it = 0; it < 16; ++it) {
            int idx = it * 256 + t;         // 0..4095
            int rr  = idx >> 5;             // 0..127  (mirror row offset)
            int cc  = idx & 31;             // chunk along mirror cols
            int orow = c0 + rr;
            if (orow < NN) {                // cols r0..r0+127 always < NN (bi<bj)
                float4 v = T4[rr * 32 + (cc ^ ((rr >> 3) & 7))];
                f32x4 pk = {v.x, v.y, v.z, v.w};
                __builtin_nontemporal_store(pk,
                    (f32x4*)(out + (size_t)orow * NN + r0 + cc * 4));
            }
        }
    }
}

// ---------------- launch ----------------

extern "C" void kernel_launch(void* const* d_in, const int* in_sizes, int n_in,
                              void* d_out, int out_size, void* d_ws, size_t ws_size,
                              hipStream_t stream) {
    const void* nf  = d_in[0];
    const void* ef  = d_in[1];
    const int*  src = (const int*)d_in[2];
    const int*  dst = (const int*)d_in[3];
    const void* W[12];
    for (int i = 0; i < 12; i++) W[i] = d_in[4 + i];

    char* ws = (char*)d_ws;
    size_t off = 0;
    auto alloc = [&](size_t bytes) -> void* {
        void* p = ws + off;
        off = (off + bytes + 255) & ~(size_t)255;
        return p;
    };
    int*   flags     = (int*)alloc(16 * sizeof(int));
    float* wf        = (float*)alloc(57920 * sizeof(float));
    int*   cnt       = (int*)alloc(NN * sizeof(int));
    int*   fill      = (int*)alloc(NN * sizeof(int));
    int*   row_start = (int*)alloc((NN + 1) * sizeof(int));
    int2*  epack     = (int2*)alloc((size_t)NE * sizeof(int2));
    float* bvec      = (float*)alloc((size_t)NN * F_EDGE * sizeof(float));
    float* h1        = (float*)alloc((size_t)NN * HID * sizeof(float));
    float* zf        = (float*)alloc((size_t)NN * LAT * sizeof(float));

    hipMemsetAsync(cnt, 0, NN * sizeof(int), stream);
    hipMemsetAsync(fill, 0, NN * sizeof(int), stream);

    k_detect<<<16, 256, 0, stream>>>(nf, ef,
        W[0], W[1], W[2], W[3], W[4], W[5], W[6], W[7], W[8], W[9], W[10], W[11],
        src, dst, flags);
    k_convert_w<<<12 * 64, 256, 0, stream>>>(
        W[0], W[1], W[2], W[3], W[4], W[5], W[6], W[7], W[8], W[9], W[10], W[11],
        flags, wf);

    k_count<<<(NE + 255) / 256, 256, 0, stream>>>(dst, flags, cnt);
    k_scan<<<1, 1024, 0, stream>>>(cnt, row_start);
    k_fill<<<(NE + 255) / 256, 256, 0, stream>>>(src, dst, flags, row_start, fill, epack);

    const float* Wn1 = wf + 0,     *bn1 = wf + 16384;
    const float* We1 = wf + 16512, *be1 = wf + 24704;
    const float* Wm1 = wf + 24832, *bm1 = wf + 41216;
    const float* Wn2 = wf + 41344, *bn2 = wf + 49536;
    const float* We2 = wf + 49600, *be2 = wf + 53696;
    const float* Wm2 = wf + 53760, *bm2 = wf + 57856;

    k_layer1<<<NN / NPB, 128, 0, stream>>>(nf, ef, flags, row_start, cnt, epack,
                                           Wn1, bn1, We1, be1, Wm1, bm1, h1, bvec);
    k_layer2<<<NN / NPB, 128, 0, stream>>>(h1, bvec, row_start, cnt, epack,
                                           Wn2, bn2, We2, be2, Wm2, bm2,
                                           zf, (float*)d_out);

    dim3 g((NN + 127) / 128, (NN + 127) / 128);
    k_adj<<<g, 256, 0, stream>>>(zf, (float*)d_out + (size_t)NN * LAT);
}